// Round 6
// baseline (1352.565 us; speedup 1.0000x reference)
//
#include <hip/hip_runtime.h>
#include <hip/hip_bf16.h>
#include <math.h>
#include <stdint.h>

#define N_NODES 100000
#define N_EDGES 3200000
#define D 64
#define NUM_RELS 20
#define HID_ATTR 32
#define OUT_ATTR 10
#define SCAN_B 391              // ceil(N_NODES / 256)

typedef __attribute__((ext_vector_type(8))) short bf16x8;
typedef __attribute__((ext_vector_type(4))) float f32x4;

static __device__ __forceinline__ unsigned short f2bf(float x) {
    unsigned u = __builtin_bit_cast(unsigned, x);
    unsigned r = (u + 0x7FFFu + ((u >> 16) & 1u)) >> 16;
    return (unsigned short)r;
}
static __device__ __forceinline__ float bf2f(unsigned short b) {
    return __builtin_bit_cast(float, (unsigned)b << 16);
}

// ---------------- CSR build (counting sort by dst) ----------------

__global__ void deg_count(const int* __restrict__ dst, int* __restrict__ deg) {
    int e = blockIdx.x * 256 + threadIdx.x;
    atomicAdd(&deg[dst[e]], 1);
}

__global__ void scan_bsum(const int* __restrict__ deg, int* __restrict__ bsum) {
    __shared__ int s[256];
    int t = threadIdx.x, i = blockIdx.x * 256 + t;
    s[t] = (i < N_NODES) ? deg[i] : 0;
    __syncthreads();
    for (int d2 = 128; d2 > 0; d2 >>= 1) {
        if (t < d2) s[t] += s[t + d2];
        __syncthreads();
    }
    if (t == 0) bsum[blockIdx.x] = s[0];
}

__global__ void scan_bbase(const int* __restrict__ bsum, int* __restrict__ bbase,
                           int* __restrict__ off) {
    __shared__ int s[512];
    int t = threadIdx.x;
    int v = (t < SCAN_B) ? bsum[t] : 0;
    s[t] = v;
    __syncthreads();
    for (int d2 = 1; d2 < 512; d2 <<= 1) {
        int x = (t >= d2) ? s[t - d2] : 0;
        __syncthreads();
        s[t] += x;
        __syncthreads();
    }
    if (t < SCAN_B) bbase[t] = s[t] - v;      // exclusive
    if (t == 0) off[N_NODES] = N_EDGES;
}

__global__ void scan_final(const int* __restrict__ deg, const int* __restrict__ bbase,
                           int* __restrict__ off, int* __restrict__ cur) {
    __shared__ int s[256];
    int t = threadIdx.x, i = blockIdx.x * 256 + t;
    int v = (i < N_NODES) ? deg[i] : 0;
    s[t] = v;
    __syncthreads();
    for (int d2 = 1; d2 < 256; d2 <<= 1) {
        int x = (t >= d2) ? s[t - d2] : 0;
        __syncthreads();
        s[t] += x;
        __syncthreads();
    }
    if (i < N_NODES) {
        int e = bbase[blockIdx.x] + s[t] - v;
        off[i] = e; cur[i] = e;
    }
}

// pack (src, rel): src < 2^17, rel < 2^5
__global__ void scatter_edges(const int* __restrict__ src, const int* __restrict__ dst,
                              const int* __restrict__ etype, int* __restrict__ cur,
                              int* __restrict__ edgedata) {
    int e = blockIdx.x * 256 + threadIdx.x;
    int d = dst[e];
    int pos = atomicAdd(&cur[d], 1);
    edgedata[pos] = src[e] | (etype[e] << 17);
}

// ---------------- dtype conversions ----------------

__global__ void f2b_kernel(const float* __restrict__ in, unsigned short* __restrict__ out,
                           int n4) {
    int i = blockIdx.x * 256 + threadIdx.x;
    if (i >= n4) return;
    float4 v = ((const float4*)in)[i];
    ushort4 o;
    o.x = f2bf(v.x); o.y = f2bf(v.y); o.z = f2bf(v.z); o.w = f2bf(v.w);
    ((ushort4*)out)[i] = o;
}

// W[r][d][o] fp32 -> Wb[r][o][d] bf16 (layout proven in round 4's transform)
__global__ void wconv_kernel(const float* __restrict__ W, unsigned short* __restrict__ Wb) {
    int r = blockIdx.x;
    for (int i = threadIdx.x; i < D * D; i += 256) {
        int d2 = i >> 6, o = i & 63;
        Wb[(size_t)r * (D * D) + o * D + d2] = f2bf(W[(size_t)r * (D * D) + d2 * D + o]);
    }
}

// ---------------- phase 1: pair-sums  agg2[q][dst][:] = sum_{e->dst, rel=r0+q} x[src] ----
// One wave per dst node. Per-rel fp32 accumulators in LDS (20 KB/block,
// lane-stride-1 -> 2-way bank aliasing = free). Random reads hit the 12.8 MB
// bf16 x buffer (L2/L3-hot). Flush = full-line 128 B bf16 rows, no atomics.
__global__ __launch_bounds__(256) void gather_pairs(
    const unsigned short* __restrict__ xb, const int* __restrict__ edgedata,
    const int* __restrict__ off, unsigned short* __restrict__ agg2,
    int r0, int rpc) {
    __shared__ float acc[4][NUM_RELS][D];
    int wave = threadIdx.x >> 6, lane = threadIdx.x & 63;
    int gw = (blockIdx.x * 256 + threadIdx.x) >> 6;
    int nw = (gridDim.x * 256) >> 6;
    float* A = &acc[wave][0][0];
    unsigned urpc = (unsigned)rpc;
    for (int v = gw; v < N_NODES; v += nw) {
        for (int r = 0; r < rpc; ++r) A[r * D + lane] = 0.f;
        int beg = off[v], end = off[v + 1];
        int i = beg;
        for (; i + 3 < end; i += 4) {
            int e0 = __builtin_amdgcn_readfirstlane(edgedata[i]);
            int e1 = __builtin_amdgcn_readfirstlane(edgedata[i + 1]);
            int e2 = __builtin_amdgcn_readfirstlane(edgedata[i + 2]);
            int e3 = __builtin_amdgcn_readfirstlane(edgedata[i + 3]);
            unsigned q0 = (unsigned)(e0 >> 17) - (unsigned)r0;
            unsigned q1 = (unsigned)(e1 >> 17) - (unsigned)r0;
            unsigned q2 = (unsigned)(e2 >> 17) - (unsigned)r0;
            unsigned q3 = (unsigned)(e3 >> 17) - (unsigned)r0;
            float x0 = 0.f, x1 = 0.f, x2 = 0.f, x3 = 0.f;
            if (q0 < urpc) x0 = bf2f(xb[(size_t)(e0 & 0x1FFFF) * D + lane]);
            if (q1 < urpc) x1 = bf2f(xb[(size_t)(e1 & 0x1FFFF) * D + lane]);
            if (q2 < urpc) x2 = bf2f(xb[(size_t)(e2 & 0x1FFFF) * D + lane]);
            if (q3 < urpc) x3 = bf2f(xb[(size_t)(e3 & 0x1FFFF) * D + lane]);
            if (q0 < urpc) A[q0 * D + lane] += x0;
            if (q1 < urpc) A[q1 * D + lane] += x1;
            if (q2 < urpc) A[q2 * D + lane] += x2;
            if (q3 < urpc) A[q3 * D + lane] += x3;
        }
        for (; i < end; ++i) {
            int e0 = __builtin_amdgcn_readfirstlane(edgedata[i]);
            unsigned q0 = (unsigned)(e0 >> 17) - (unsigned)r0;
            if (q0 < urpc) {
                float x0 = bf2f(xb[(size_t)(e0 & 0x1FFFF) * D + lane]);
                A[q0 * D + lane] += x0;
            }
        }
        for (int r = 0; r < rpc; ++r)
            agg2[((size_t)r * N_NODES + v) * D + lane] = f2bf(A[r * D + lane]);
    }
}

// ---------------- phase 2: dense multi-rel MFMA  h[tile] (+)= sum_q S_q @ W_{r0+q} ----
// Frag layouts identical to round-4's verified transform_mfma.
// first: don't read hbuf. lastmode: 0 = store hbuf f32; 1 = relu -> xbout bf16;
// 2 = store h2out f32.
__global__ __launch_bounds__(256) void transform2(
    const unsigned short* __restrict__ agg2, const unsigned short* __restrict__ Wb,
    int r0, int rpc, float* __restrict__ hbuf, unsigned short* __restrict__ xbout,
    float* __restrict__ h2out, int first, int lastmode) {
    int wave = threadIdx.x >> 6, lane = threadIdx.x & 63;
    int tile = blockIdx.x * 4 + wave;
    if (tile >= N_NODES / 16) return;
    int n0 = tile * 16, lrow = lane & 15, lhi = lane >> 4;

    f32x4 C[4];
#pragma unroll
    for (int ot = 0; ot < 4; ++ot) C[ot] = (f32x4){0.f, 0.f, 0.f, 0.f};

    for (int q = 0; q < rpc; ++q) {
        const unsigned short* S = agg2 + ((size_t)q * N_NODES + n0) * D;
        const unsigned short* xrow = S + lrow * D + lhi * 8;
        bf16x8 a0 = *(const bf16x8*)(xrow);
        bf16x8 a1 = *(const bf16x8*)(xrow + 32);
        const unsigned short* Wr = Wb + ((size_t)(r0 + q) << 12);
#pragma unroll
        for (int ot = 0; ot < 4; ++ot) {
            const unsigned short* wrow = Wr + (size_t)(ot * 16 + lrow) * D + lhi * 8;
            bf16x8 b0 = *(const bf16x8*)(wrow);
            bf16x8 b1 = *(const bf16x8*)(wrow + 32);
            C[ot] = __builtin_amdgcn_mfma_f32_16x16x32_bf16(a0, b0, C[ot], 0, 0, 0);
            C[ot] = __builtin_amdgcn_mfma_f32_16x16x32_bf16(a1, b1, C[ot], 0, 0, 0);
        }
    }
#pragma unroll
    for (int ot = 0; ot < 4; ++ot)
#pragma unroll
        for (int reg = 0; reg < 4; ++reg) {
            int node = n0 + lhi * 4 + reg;
            size_t idx = (size_t)node * D + ot * 16 + lrow;
            float val = C[ot][reg];
            if (!first) val += hbuf[idx];
            if (lastmode == 0) hbuf[idx] = val;
            else if (lastmode == 1) xbout[idx] = f2bf(fmaxf(val, 0.f));
            else h2out[idx] = val;
        }
}

// ---------------- readout ----------------

__global__ void colsum_kernel(const float* __restrict__ h2,
                              float* __restrict__ g, int n) {
    __shared__ float s[256];
    int tid = threadIdx.x;
    int col = tid & 63;
    int rowgrp = (blockIdx.x * blockDim.x + tid) >> 6;
    int nrowgrp = (gridDim.x * blockDim.x) >> 6;
    float acc = 0.0f;
    for (int row = rowgrp; row < n; row += nrowgrp)
        acc += h2[(size_t)row * D + col];
    s[tid] = acc;
    __syncthreads();
    if (tid < 64) {
        acc = s[tid] + s[tid + 64] + s[tid + 128] + s[tid + 192];
        atomicAdd(&g[col], acc);
    }
}

__global__ void mlp_kernel(const float* __restrict__ g,
                           const float* __restrict__ A1w,
                           const float* __restrict__ A1b,
                           const float* __restrict__ A2w,
                           const float* __restrict__ A2b,
                           float* __restrict__ out, float invN) {
    __shared__ float a1[HID_ATTR];
    int t = threadIdx.x;
    if (t < HID_ATTR) {
        float acc = A1b[t];
#pragma unroll
        for (int d2 = 0; d2 < D; ++d2)
            acc = fmaf(g[d2] * invN, A1w[d2 * HID_ATTR + t], acc);
        a1[t] = fmaxf(acc, 0.0f);
    }
    __syncthreads();
    if (t < OUT_ATTR) {
        float acc = A2b[t];
#pragma unroll
        for (int j = 0; j < HID_ATTR; ++j)
            acc = fmaf(a1[j], A2w[j * OUT_ATTR + t], acc);
        out[t] = 1.0f / (1.0f + expf(-acc));
    }
}

// ---------------- launch ----------------

extern "C" void kernel_launch(void* const* d_in, const int* in_sizes, int n_in,
                              void* d_out, int out_size, void* d_ws, size_t ws_size,
                              hipStream_t stream) {
    const float* h   = (const float*)d_in[0];
    const int* src   = (const int*)d_in[1];
    const int* dst   = (const int*)d_in[2];
    const int* etype = (const int*)d_in[3];
    const float* W1  = (const float*)d_in[4];
    const float* W2  = (const float*)d_in[5];
    const float* A1w = (const float*)d_in[6];
    const float* A1b = (const float*)d_in[7];
    const float* A2w = (const float*)d_in[8];
    const float* A2b = (const float*)d_in[9];

    float* out_h2 = (float*)d_out;
    float* out_a  = out_h2 + (size_t)N_NODES * D;

    // workspace layout
    float* hbuf   = (float*)d_ws;                         // 6,400,000 f32
    float* gsum   = hbuf + (size_t)N_NODES * D;           // 64
    int* deg      = (int*)(gsum + 64);                    // 100,000
    int* off      = deg + N_NODES;                        // 100,004
    int* cur      = off + (N_NODES + 4);                  // 100,000
    int* bsum     = cur + N_NODES;                        // 512
    int* bbase    = bsum + 512;                           // 512
    int* edgedata = bbase + 512;                          // 3,200,000
    unsigned short* xb  = (unsigned short*)(edgedata + N_EDGES);  // 6,400,000 u16
    unsigned short* w1b = xb + (size_t)N_NODES * D;       // 81,920 u16
    unsigned short* w2b = w1b + NUM_RELS * D * D;         // 81,920 u16
    unsigned short* agg2 = (unsigned short*)
        (((uintptr_t)(w2b + NUM_RELS * D * D) + 255) & ~(uintptr_t)255);

    const size_t fixedB = (size_t)((char*)agg2 - (char*)d_ws);
    const size_t slabB  = (size_t)N_NODES * D * 2;        // 12.8 MB per relation
    int RPC = 1;
    if (ws_size >= fixedB + 20 * slabB) RPC = 20;
    else if (ws_size >= fixedB + 10 * slabB) RPC = 10;
    else if (ws_size >= fixedB + 5 * slabB) RPC = 5;
    else if (ws_size >= fixedB + 2 * slabB) RPC = 2;
    int NC = NUM_RELS / RPC;

    hipMemsetAsync(deg, 0, N_NODES * sizeof(int), stream);
    hipMemsetAsync(gsum, 0, 64 * sizeof(float), stream);

    // CSR by dst + weight conversion + x -> bf16
    deg_count<<<N_EDGES / 256, 256, 0, stream>>>(dst, deg);
    scan_bsum<<<SCAN_B, 256, 0, stream>>>(deg, bsum);
    scan_bbase<<<1, 512, 0, stream>>>(bsum, bbase, off);
    scan_final<<<SCAN_B, 256, 0, stream>>>(deg, bbase, off, cur);
    scatter_edges<<<N_EDGES / 256, 256, 0, stream>>>(src, dst, etype, cur, edgedata);
    wconv_kernel<<<NUM_RELS, 256, 0, stream>>>(W1, w1b);
    wconv_kernel<<<NUM_RELS, 256, 0, stream>>>(W2, w2b);
    f2b_kernel<<<(N_NODES * D / 4 + 255) / 256, 256, 0, stream>>>(h, xb, N_NODES * D / 4);

    const int TGRID = (N_NODES / 16 + 3) / 4;             // 1563

    // layer 1: pair-sums -> MFMA transform; last chunk emits relu'd bf16 xb
    for (int c = 0; c < NC; ++c) {
        gather_pairs<<<2048, 256, 0, stream>>>(xb, edgedata, off, agg2, c * RPC, RPC);
        transform2<<<TGRID, 256, 0, stream>>>(agg2, w1b, c * RPC, RPC, hbuf, xb,
                                              nullptr, c == 0,
                                              (c == NC - 1) ? 1 : 0);
    }
    // layer 2: last chunk writes out_h2 fp32
    for (int c = 0; c < NC; ++c) {
        gather_pairs<<<2048, 256, 0, stream>>>(xb, edgedata, off, agg2, c * RPC, RPC);
        transform2<<<TGRID, 256, 0, stream>>>(agg2, w2b, c * RPC, RPC, hbuf, nullptr,
                                              out_h2, c == 0,
                                              (c == NC - 1) ? 2 : 0);
    }

    // readout
    colsum_kernel<<<512, 256, 0, stream>>>(out_h2, gsum, N_NODES);
    mlp_kernel<<<1, 64, 0, stream>>>(gsum, A1w, A1b, A2w, A2b,
                                     out_a, 1.0f / (float)N_NODES);
}